// Round 3
// baseline (32.111 us; speedup 1.0000x reference)
//
#include <hip/hip_runtime.h>

// FutureEncoder: out[b,t,:] = sum_j softmax_j(dot(x[b,t], x[b,t+1+j])) * x[b,t+1+j],
// j in [0,16), valid iff t+1+j < S. fp32 throughout.
//
// Round 3: attack the memory system, not the ALU chain.
//  - XCD-aware block swizzle: 8 contiguous t-strips, one per XCD, so adjacent
//    t's (which share 16/17 window rows) reuse the same per-XCD 4MB L2.
//    Without this, round-robin dispatch spreads neighbors across XCDs and all
//    ~311MB of window re-reads hit Infinity Cache (~the observed 31us).
//  - TPW 2 -> 4: 19 rows per wave for 4 t's = 4.75 rows/t, halving L2 read
//    traffic (~155MB). VGPR ~210 -> 2 waves/SIMD.
// HBM floor: 33.5MB in + 33.5MB out = ~10.6us.

namespace {
constexpr int kB   = 2;
constexpr int kS   = 4096;
constexpr int kH   = 1024;
constexpr int kK   = 16;
constexpr int kTPW = 4;                 // t's per wave
constexpr int kC   = 2;                 // window rows per chunk
constexpr int kFR  = kH / (64 * 4);     // float4 fragments per lane per row = 4
constexpr int kNV  = kTPW * kC;         // scores per chunk = 8
constexpr int kXCD = 8;
constexpr int kTPB = 4 * kTPW;          // t's per block (4 waves) = 16
constexpr int kBlocks = kB * kS / kTPB; // 512
}

__global__ __launch_bounds__(256, 2)
void future_encoder_kernel(const float* __restrict__ x, float* __restrict__ out) {
  const int lane = (int)(threadIdx.x & 63);
  const int wib  = (int)(threadIdx.x >> 6);          // wave in block, 0..3

  // XCD swizzle: physical block n -> XCD n%8 (HW round-robin). Give XCD q the
  // contiguous virtual-block strip [q*64, q*64+64): vb = (n%8)*64 + n/8.
  const int vb  = (int)(blockIdx.x % kXCD) * (kBlocks / kXCD) + (int)(blockIdx.x / kXCD);
  const int t0g = vb * kTPB + wib * kTPW;            // first t of this wave
  const int b   = t0g / kS;
  const int tl0 = t0g % kS;                          // 16 | 4096: never crosses batches
  const float* __restrict__ xb = x   + (size_t)b * kS * kH;
  float* __restrict__       ob = out + (size_t)b * kS * kH;
  const int col = lane * 4;

  // Query fragments: lane holds elements {p*256 + lane*4 .. +3}
  float4 xt[kTPW][kFR];
#pragma unroll
  for (int tt = 0; tt < kTPW; ++tt)
#pragma unroll
    for (int p = 0; p < kFR; ++p)
      xt[tt][p] = *(const float4*)(xb + (size_t)(tl0 + tt) * kH + p * 256 + col);

  // Online-softmax state per t
  float m[kTPW], s[kTPW];
  float4 acc[kTPW][kFR];
#pragma unroll
  for (int tt = 0; tt < kTPW; ++tt) {
    m[tt] = -1e30f;
    s[tt] = 0.f;
#pragma unroll
    for (int p = 0; p < kFR; ++p) acc[tt][p] = make_float4(0.f, 0.f, 0.f, 0.f);
  }

  const int rBeg = tl0 + 1;
  const int rEnd = min(tl0 + kTPW - 1 + kK, kS - 1);  // inclusive

  for (int r0 = rBeg; r0 <= rEnd; r0 += kC) {
    // ---- load chunk (independent loads; clamped rows masked at update) ----
    float4 w[kC][kFR];
#pragma unroll
    for (int i = 0; i < kC; ++i) {
      const int r = min(r0 + i, rEnd);
#pragma unroll
      for (int p = 0; p < kFR; ++p)
        w[i][p] = *(const float4*)(xb + (size_t)r * kH + p * 256 + col);
    }

    // ---- partial dots (2 accumulators to shorten the fma chain) ----
    float sc[kNV];
#pragma unroll
    for (int tt = 0; tt < kTPW; ++tt)
#pragma unroll
      for (int i = 0; i < kC; ++i) {
        float a0 = 0.f, a1 = 0.f;
#pragma unroll
        for (int p = 0; p < kFR; ++p) {
          a0 = fmaf(xt[tt][p].x, w[i][p].x, a0);
          a1 = fmaf(xt[tt][p].y, w[i][p].y, a1);
          a0 = fmaf(xt[tt][p].z, w[i][p].z, a0);
          a1 = fmaf(xt[tt][p].w, w[i][p].w, a1);
        }
        sc[tt * kC + i] = a0 + a1;
      }

    // ---- batched butterfly: 8 independent chains pipeline per level ----
#pragma unroll
    for (int off = 32; off >= 1; off >>= 1) {
      float other[kNV];
#pragma unroll
      for (int v = 0; v < kNV; ++v) other[v] = __shfl_xor(sc[v], off, 64);
#pragma unroll
      for (int v = 0; v < kNV; ++v) sc[v] += other[v];
    }

    // ---- online updates (scores wave-uniform -> uniform branches) ----
#pragma unroll
    for (int tt = 0; tt < kTPW; ++tt)
#pragma unroll
      for (int i = 0; i < kC; ++i) {
        const int r = r0 + i;
        const int d = r - tl0 - tt;
        if (r <= rEnd && d >= 1 && d <= kK) {
          const float v = sc[tt * kC + i];
          if (v <= m[tt]) {
            const float p2 = __expf(v - m[tt]);
            s[tt] += p2;
#pragma unroll
            for (int p = 0; p < kFR; ++p) {
              acc[tt][p].x = fmaf(p2, w[i][p].x, acc[tt][p].x);
              acc[tt][p].y = fmaf(p2, w[i][p].y, acc[tt][p].y);
              acc[tt][p].z = fmaf(p2, w[i][p].z, acc[tt][p].z);
              acc[tt][p].w = fmaf(p2, w[i][p].w, acc[tt][p].w);
            }
          } else {
            const float r2 = __expf(m[tt] - v);   // 0 on first valid row
            m[tt] = v;
            s[tt] = fmaf(s[tt], r2, 1.f);
#pragma unroll
            for (int p = 0; p < kFR; ++p) {
              acc[tt][p].x = fmaf(acc[tt][p].x, r2, w[i][p].x);
              acc[tt][p].y = fmaf(acc[tt][p].y, r2, w[i][p].y);
              acc[tt][p].z = fmaf(acc[tt][p].z, r2, w[i][p].z);
              acc[tt][p].w = fmaf(acc[tt][p].w, r2, w[i][p].w);
            }
          }
        }
      }
  }

  // ---- epilogue: out = acc / s  (s==0 only for t==S-1 -> exact zeros) ----
#pragma unroll
  for (int tt = 0; tt < kTPW; ++tt) {
    const float inv = (s[tt] > 0.f) ? (1.f / s[tt]) : 0.f;
#pragma unroll
    for (int p = 0; p < kFR; ++p) {
      float4 o;
      o.x = acc[tt][p].x * inv;
      o.y = acc[tt][p].y * inv;
      o.z = acc[tt][p].z * inv;
      o.w = acc[tt][p].w * inv;
      *(float4*)(ob + (size_t)(tl0 + tt) * kH + p * 256 + col) = o;
    }
  }
}

extern "C" void kernel_launch(void* const* d_in, const int* in_sizes, int n_in,
                              void* d_out, int out_size, void* d_ws, size_t ws_size,
                              hipStream_t stream) {
  const float* x = (const float*)d_in[0];
  float* out = (float*)d_out;
  hipLaunchKernelGGL(future_encoder_kernel, dim3(kBlocks), dim3(256), 0, stream,
                     x, out);
}